// Round 1
// 332.089 us; speedup vs baseline: 1.0074x; 1.0074x over previous
//
#include <hip/hip_runtime.h>

#define N_IMG 2048
#define SRC   64
#define TH    128
#define TW    128
// Padded LDS image: source cols/rows -2..65 stored at 0..67 (2-wide zero ring).
// clamp(x0, -2, 64) then +2 => all four bilinear corners read in-bounds, and
// every invalid/pad corner reads a structural zero. No per-corner masks.
#define LW    68
#define LN    (LW * LW)   // 4624 floats = 18496 B per image

#define BLK   512         // 8 waves/block; LDS (37 KB) still allows 4 blocks/CU
                          // => 32 waves/CU (occupancy cap) vs 16 at 256 threads.

typedef float v2f __attribute__((ext_vector_type(2)));

__global__ __launch_bounds__(BLK) void affine_sample_kernel(
    const float* __restrict__ affine,
    const float* __restrict__ fill,
    const float* __restrict__ stroke,
    float* __restrict__ out)
{
    __shared__ float sF[LN];
    __shared__ float sS[LN];   // static offset from sF => shared vaddr, imm offsets

    const int n   = blockIdx.x;
    const int tid = threadIdx.x;

    // --- Theta first: independent scalar work to overlap with staging latency.
    const float t0 = affine[n * 6 + 0];
    const float t1 = affine[n * 6 + 1];
    const float t2 = affine[n * 6 + 2];
    const float t3 = affine[n * 6 + 3];
    const float t4 = affine[n * 6 + 4];
    const float t5 = affine[n * 6 + 5];
    const float a00 = 2.0f / (1.0f + __expf(-t0));
    const float a11 = 2.0f / (1.0f + __expf(-t1));
    const float a01 = 2.0f * tanhf(t2);
    const float a10 = 2.0f * tanhf(t3);
    const float a02 = tanhf(t4);
    const float a12 = tanhf(t5);

    // --- Zero the 2-wide border ring (disjoint from interior; one sync later).
    // rows 0,1,66,67 (full width): 2*68 = 136 index pairs
    for (int i = tid; i < 136; i += BLK) {
        const int r = i / LW, c = i % LW;          // r in {0,1}
        sF[r * LW + c] = 0.f;  sF[(67 - r) * LW + c] = 0.f;
        sS[r * LW + c] = 0.f;  sS[(67 - r) * LW + c] = 0.f;
    }
    // cols 0,1,66,67 for rows 2..65: 64*2 = 128 index pairs
    for (int i = tid; i < 128; i += BLK) {
        const int r = 2 + (i >> 1), c = i & 1;     // c in {0,1}
        sF[r * LW + c] = 0.f;  sF[r * LW + 67 - c] = 0.f;
        sS[r * LW + c] = 0.f;  sS[r * LW + 67 - c] = 0.f;
    }

    // --- Stage interior with float4 global loads (coalesced).
    const float* __restrict__ fptr = fill   + (size_t)n * SRC * SRC;
    const float* __restrict__ sptr = stroke + (size_t)n * SRC * SRC;
    for (int i = tid; i < SRC * SRC / 4; i += BLK) {
        const float4 f = reinterpret_cast<const float4*>(fptr)[i];
        const float4 s = reinterpret_cast<const float4*>(sptr)[i];
        const int y  = i >> 4;            // 16 groups of 4 per 64-wide row
        const int x4 = (i & 15) << 2;
        const int d  = (y + 2) * LW + x4 + 2;
        sF[d] = f.x; sF[d + 1] = f.y; sF[d + 2] = f.z; sF[d + 3] = f.w;
        sS[d] = s.x; sS[d + 1] = s.y; sS[d + 2] = s.z; sS[d + 3] = s.w;
    }

    __syncthreads();

    float* __restrict__ outF = out + (size_t)n * TH * TW;
    float* __restrict__ outS = out + (size_t)N_IMG * TH * TW + (size_t)n * TH * TW;

    const int lane = tid & 31;   // x position within a 32-wide column group
    const int rsub = tid >> 5;   // 16 row sub-blocks per iteration

    // isx = a00*(px+0.5) + Cx(row), source coords with PAD folded in.
    for (int it = 0; it < 8; ++it) {
        const int py = it * 16 + rsub;
        const float Y  = ((float)py + 0.5f) * (2.0f / TH) - 1.0f;
        const float Cx = 64.0f * (a01 * Y + a02 - a00) + 31.5f;
        const float Cy = 64.0f * (a11 * Y + a12 - a10) + 31.5f;
        float* __restrict__ oF = outF + py * TW + lane;
        float* __restrict__ oS = outS + py * TW + lane;

        #pragma unroll
        for (int j = 0; j < 4; ++j) {
            const float fx  = (float)(lane + 32 * j) + 0.5f;
            const float isx = fmaf(a00, fx, Cx);
            const float isy = fmaf(a10, fx, Cy);

            const float x0f = floorf(isx);
            const float y0f = floorf(isy);
            const float wx  = isx - x0f;
            const float wy  = isy - y0f;

            // clamp into the zero-ringed LDS image; invalid corners read 0
            const int xc = min(max((int)x0f, -2), 64);
            const int yc = min(max((int)y0f, -2), 64);
            const int idx = (yc + 2) * LW + (xc + 2);

            v2f v00 = { sF[idx],          sS[idx]          };
            v2f v10 = { sF[idx + 1],      sS[idx + 1]      };
            v2f v01 = { sF[idx + LW],     sS[idx + LW]     };
            v2f v11 = { sF[idx + LW + 1], sS[idx + LW + 1] };

            const float wxa = 1.0f - wx;
            const float wya = 1.0f - wy;
            v2f r = (wxa * wya) * v00 + (wx * wya) * v10
                  + (wxa * wy ) * v01 + (wx * wy ) * v11;

            oF[32 * j] = r.x;   // coalesced dword stores (lanes stride 1)
            oS[32 * j] = r.y;
        }
    }
}

extern "C" void kernel_launch(void* const* d_in, const int* in_sizes, int n_in,
                              void* d_out, int out_size, void* d_ws, size_t ws_size,
                              hipStream_t stream) {
    const float* affine = (const float*)d_in[0];  // (N, 6)
    const float* fill   = (const float*)d_in[1];  // (N, 64, 64)
    const float* stroke = (const float*)d_in[2];  // (N, 64, 64)
    // d_in[3] = targetsize, unused by the computation.
    float* out = (float*)d_out;                   // fill_out then stroke_out, each (N,128,128)

    affine_sample_kernel<<<dim3(N_IMG), dim3(BLK), 0, stream>>>(affine, fill, stroke, out);
}

// Round 2
// 331.632 us; speedup vs baseline: 1.0088x; 1.0014x over previous
//
#include <hip/hip_runtime.h>

#define N_IMG 2048
#define SRC   64
#define TH    128
#define TW    128
// Padded LDS image, fill/stroke INTERLEAVED as {F,S} pairs (8 B per pixel).
// Source cols/rows -2..65 stored at 0..67 (2-wide zero ring).
// clamp(x0, -2, 64) then +2 => all four bilinear corners read in-bounds, and
// every invalid/pad corner reads a structural zero. No per-corner masks.
// Interleaving => each row's corner pair {F[x],S[x],F[x+1],S[x+1]} is 16
// contiguous 8B-aligned bytes => one ds_read2_b64 per row instead of 4 b32.
#define LW    68
#define LN    (LW * LW)        // 4624 pixel-pairs
#define BLK   512              // 8 waves/block; LDS 36992 B => 4 blocks/CU, 32 waves/CU

typedef float v2f __attribute__((ext_vector_type(2)));

__global__ __launch_bounds__(BLK) void affine_sample_kernel(
    const float* __restrict__ affine,
    const float* __restrict__ fill,
    const float* __restrict__ stroke,
    float* __restrict__ out)
{
    __shared__ float sFS[LN * 2];   // interleaved {F,S}; 36992 B

    const int n   = blockIdx.x;
    const int tid = threadIdx.x;

    // --- Theta first: independent scalar work to overlap with staging latency.
    const float t0 = affine[n * 6 + 0];
    const float t1 = affine[n * 6 + 1];
    const float t2 = affine[n * 6 + 2];
    const float t3 = affine[n * 6 + 3];
    const float t4 = affine[n * 6 + 4];
    const float t5 = affine[n * 6 + 5];
    const float a00 = 2.0f / (1.0f + __expf(-t0));
    const float a11 = 2.0f / (1.0f + __expf(-t1));
    const float a01 = 2.0f * tanhf(t2);
    const float a10 = 2.0f * tanhf(t3);
    const float a02 = tanhf(t4);
    const float a12 = tanhf(t5);

    // --- Zero the 2-wide border ring (disjoint from interior; one sync later).
    const v2f z2 = {0.f, 0.f};
    // rows 0,1,66,67 (full width): 2*68 = 136 index pairs
    for (int i = tid; i < 136; i += BLK) {
        const int r = i / LW, c = i % LW;          // r in {0,1}
        *(v2f*)&sFS[(r * LW + c) * 2]        = z2;
        *(v2f*)&sFS[((67 - r) * LW + c) * 2] = z2;
    }
    // cols 0,1,66,67 for rows 2..65: 64*2 = 128 index pairs
    for (int i = tid; i < 128; i += BLK) {
        const int r = 2 + (i >> 1), c = i & 1;     // c in {0,1}
        *(v2f*)&sFS[(r * LW + c) * 2]        = z2;
        *(v2f*)&sFS[(r * LW + 67 - c) * 2]   = z2;
    }

    // --- Stage interior with float4 global loads (coalesced), interleave into LDS.
    // d*4 bytes = 8*((y+2)*68 + x4+2); inner value even => 16-B aligned b128 writes.
    const float* __restrict__ fptr = fill   + (size_t)n * SRC * SRC;
    const float* __restrict__ sptr = stroke + (size_t)n * SRC * SRC;
    for (int i = tid; i < SRC * SRC / 4; i += BLK) {
        const float4 f = reinterpret_cast<const float4*>(fptr)[i];
        const float4 s = reinterpret_cast<const float4*>(sptr)[i];
        const int y  = i >> 4;            // 16 groups of 4 per 64-wide row
        const int x4 = (i & 15) << 2;
        const int d  = ((y + 2) * LW + x4 + 2) * 2;
        const float4 lo = {f.x, s.x, f.y, s.y};
        const float4 hi = {f.z, s.z, f.w, s.w};
        *(float4*)&sFS[d]     = lo;
        *(float4*)&sFS[d + 4] = hi;
    }

    __syncthreads();

    float* __restrict__ outF = out + (size_t)n * TH * TW;
    float* __restrict__ outS = out + (size_t)N_IMG * TH * TW + (size_t)n * TH * TW;

    const int lane = tid & 31;   // x position within a 32-wide column group
    const int rsub = tid >> 5;   // 16 row sub-blocks per iteration

    // isx = a00*(px+0.5) + Cx(row), source coords with PAD folded in.
    for (int it = 0; it < 8; ++it) {
        const int py = it * 16 + rsub;
        const float Y  = ((float)py + 0.5f) * (2.0f / TH) - 1.0f;
        const float Cx = 64.0f * (a01 * Y + a02 - a00) + 31.5f;
        const float Cy = 64.0f * (a11 * Y + a12 - a10) + 31.5f;
        float* __restrict__ oF = outF + py * TW + lane;
        float* __restrict__ oS = outS + py * TW + lane;

        #pragma unroll
        for (int j = 0; j < 4; ++j) {
            const float fx  = (float)(lane + 32 * j) + 0.5f;
            const float isx = fmaf(a00, fx, Cx);
            const float isy = fmaf(a10, fx, Cy);

            const float x0f = floorf(isx);
            const float y0f = floorf(isy);
            const float wx  = isx - x0f;
            const float wy  = isy - y0f;

            // clamp into the zero-ringed LDS image; invalid corners read 0
            const int xc = min(max((int)x0f, -2), 64);
            const int yc = min(max((int)y0f, -2), 64);
            const int idx2 = ((yc + 2) * LW + (xc + 2)) * 2;

            // Two adjacent v2f loads per row => compiler merges to ds_read2_b64
            // (offsets 0/1 for row y0, 68/69 for row y0+1, in 8-B units).
            const v2f v00 = *(const v2f*)&sFS[idx2];
            const v2f v10 = *(const v2f*)&sFS[idx2 + 2];
            const v2f v01 = *(const v2f*)&sFS[idx2 + 2 * LW];
            const v2f v11 = *(const v2f*)&sFS[idx2 + 2 * LW + 2];

            const float wxa = 1.0f - wx;
            const float wya = 1.0f - wy;
            v2f r = (wxa * wya) * v00 + (wx * wya) * v10
                  + (wxa * wy ) * v01 + (wx * wy ) * v11;

            oF[32 * j] = r.x;   // coalesced dword stores (lanes stride 1)
            oS[32 * j] = r.y;
        }
    }
}

extern "C" void kernel_launch(void* const* d_in, const int* in_sizes, int n_in,
                              void* d_out, int out_size, void* d_ws, size_t ws_size,
                              hipStream_t stream) {
    const float* affine = (const float*)d_in[0];  // (N, 6)
    const float* fill   = (const float*)d_in[1];  // (N, 64, 64)
    const float* stroke = (const float*)d_in[2];  // (N, 64, 64)
    // d_in[3] = targetsize, unused by the computation.
    float* out = (float*)d_out;                   // fill_out then stroke_out, each (N,128,128)

    affine_sample_kernel<<<dim3(N_IMG), dim3(BLK), 0, stream>>>(affine, fill, stroke, out);
}